// Round 12
// baseline (19058.344 us; speedup 1.0000x reference)
//
#include <hip/hip_runtime.h>

#define NROWS 32768   // B*T = 16*2048
#define DIM 256
#define KCODES 1024
#define NLEV 4
#define CAP 16
#define MARGIN 8e-3f

typedef short short8v __attribute__((ext_vector_type(8)));
typedef float f32x4v  __attribute__((ext_vector_type(4)));

// bf16 round-to-nearest-even
static __device__ __forceinline__ unsigned short f2bf(float f) {
  unsigned u = __float_as_uint(f);
  unsigned lsb = (u >> 16) & 1u;
  u += 0x7fffu + lsb;
  return (unsigned short)(u >> 16);
}

// ============ codebook squared norms (unchanged, verified) ============
__global__ __launch_bounds__(256) void k_bnorm(const float* __restrict__ cb,
                                               float* __restrict__ bv) {
  int r = blockIdx.x * blockDim.x + threadIdx.x;
  if (r >= NLEV * KCODES) return;
  const float4* p = reinterpret_cast<const float4*>(cb + (size_t)r * DIM);
  float s0 = 0.f, s1 = 0.f, s2 = 0.f, s3 = 0.f;
  for (int g = 0; g < DIM / 4; ++g) {
    float4 v = p[g];
    s0 += v.x * v.x; s1 += v.y * v.y; s2 += v.z * v.z; s3 += v.w * v.w;
  }
  bv[r] = (s0 + s1) + (s2 + s3);
}

// ============ codebook -> bf16 (chi), all levels ============
__global__ __launch_bounds__(256) void k_csplit(const float* __restrict__ cb,
                                                unsigned short* __restrict__ chi) {
  const int tid = threadIdx.x;
  const int cr = blockIdx.x * 16 + (tid >> 4);  // 0..4095
  const int l16 = tid & 15;
  const float4* p = reinterpret_cast<const float4*>(cb + (size_t)cr * DIM + l16 * 16);
  unsigned w[8];
  #pragma unroll
  for (int j = 0; j < 4; ++j) {
    float4 v = p[j];
    w[2 * j + 0] = (unsigned)f2bf(v.x) | ((unsigned)f2bf(v.y) << 16);
    w[2 * j + 1] = (unsigned)f2bf(v.z) | ((unsigned)f2bf(v.w) << 16);
  }
  unsigned* o = reinterpret_cast<unsigned*>(chi + (size_t)cr * DIM + l16 * 16);
  #pragma unroll
  for (int k = 0; k < 8; ++k) o[k] = w[k];
}

// ============ x -> rowsq + rhi (bf16 of level-0 residual) ============
__global__ __launch_bounds__(256) void k_prep(const float* __restrict__ x,
                                              unsigned short* __restrict__ rhi,
                                              float* __restrict__ rowsq) {
  __shared__ float sred[256];
  const int tid = threadIdx.x;
  const int row = blockIdx.x * 16 + (tid >> 4);
  const int l16 = tid & 15;
  const float4* p = reinterpret_cast<const float4*>(x + (size_t)row * DIM + l16 * 16);
  float e = 0.f;
  unsigned w[8];
  #pragma unroll
  for (int j = 0; j < 4; ++j) {
    float4 v = p[j];
    e += v.x * v.x + v.y * v.y + v.z * v.z + v.w * v.w;
    w[2 * j + 0] = (unsigned)f2bf(v.x) | ((unsigned)f2bf(v.y) << 16);
    w[2 * j + 1] = (unsigned)f2bf(v.z) | ((unsigned)f2bf(v.w) << 16);
  }
  unsigned* o = reinterpret_cast<unsigned*>(rhi + (size_t)row * DIM + l16 * 16);
  #pragma unroll
  for (int k = 0; k < 8; ++k) o[k] = w[k];
  sred[tid] = e;
  __syncthreads();
  if (tid < 16) {
    float s = 0.f;
    #pragma unroll
    for (int k = 0; k < 16; ++k) s += sred[tid * 16 + k];
    rowsq[blockIdx.x * 16 + tid] = s;
  }
}

// ============ MFMA bf16 screen, one level ============
// 512 blocks x 512 thr (8 waves). Block = 64 rows x 1024 codes.
// wave w: rows row0 = blk*64 + (w>>2)*32 (32 rows), codes c0 = (w&3)*256.
// acc[2][16] 16x16 C-tiles; K-loop 8 steps of 32. Guaranteed |d_s - d_exact|
// <= 3.2e-3 (bf16 RNE on r,c + fp32 MFMA accum); survivors within MARGIN=8e-3
// of screen-min provably contain the true argmin. Overflow (>CAP) -> exact
// kernel full-scans that row.
__global__ __launch_bounds__(512) void k_screen(const unsigned short* __restrict__ rhi,
                                                const unsigned short* __restrict__ chi_l,
                                                const float* __restrict__ bv_l,
                                                const float* __restrict__ rowsq,
                                                unsigned* __restrict__ survq,
                                                unsigned* __restrict__ counts) {
  __shared__ float minb[64][4];
  __shared__ float rowminf[64];
  __shared__ unsigned cnt[64];
  const int tid = threadIdx.x;
  const int lane = tid & 63;
  const int w = tid >> 6;
  const int rh2 = w >> 2;
  const int cg = w & 3;
  const int row0 = blockIdx.x * 64 + rh2 * 32;
  const int c0 = cg * 256;
  const int ln = lane & 15;
  const int kb = lane >> 4;

  f32x4v acc[2][16];
  #pragma unroll
  for (int r = 0; r < 2; ++r)
    #pragma unroll
    for (int t = 0; t < 16; ++t) acc[r][t] = (f32x4v){0.f, 0.f, 0.f, 0.f};

  const unsigned short* aptr0 = rhi + (size_t)(row0 + ln) * DIM + kb * 8;
  const unsigned short* aptr1 = aptr0 + 16 * DIM;
  const unsigned short* bptr = chi_l + (size_t)(c0 + ln) * DIM + kb * 8;

  #pragma unroll 1
  for (int ks = 0; ks < 8; ++ks) {
    short8v a0 = *reinterpret_cast<const short8v*>(aptr0 + ks * 32);
    short8v a1 = *reinterpret_cast<const short8v*>(aptr1 + ks * 32);
    #pragma unroll
    for (int t = 0; t < 16; ++t) {
      short8v b = *reinterpret_cast<const short8v*>(bptr + (size_t)t * 16 * DIM + ks * 32);
      acc[0][t] = __builtin_amdgcn_mfma_f32_16x16x32_bf16(a0, b, acc[0][t], 0, 0, 0);
      acc[1][t] = __builtin_amdgcn_mfma_f32_16x16x32_bf16(a1, b, acc[1][t], 0, 0, 0);
    }
  }

  // screen distances + per-row min. C/D: col=lane&15, row=(lane>>4)*4+reg.
  float bvl[16];
  #pragma unroll
  for (int t = 0; t < 16; ++t) bvl[t] = bv_l[c0 + t * 16 + ln];
  float rq[2][4];
  #pragma unroll
  for (int r = 0; r < 2; ++r)
    #pragma unroll
    for (int g = 0; g < 4; ++g) rq[r][g] = rowsq[row0 + r * 16 + kb * 4 + g];

  #pragma unroll
  for (int r = 0; r < 2; ++r) {
    #pragma unroll
    for (int g = 0; g < 4; ++g) {
      float v = __builtin_inff();
      #pragma unroll
      for (int t = 0; t < 16; ++t) {
        float dd = (rq[r][g] + bvl[t]) - 2.0f * acc[r][t][g];
        v = fminf(v, dd);
      }
      #pragma unroll
      for (int m = 1; m < 16; m <<= 1) v = fminf(v, __shfl_xor(v, m));
      if (ln == 0) minb[rh2 * 32 + r * 16 + kb * 4 + g][cg] = v;
    }
  }
  __syncthreads();
  if (tid < 64) {
    rowminf[tid] = fminf(fminf(minb[tid][0], minb[tid][1]),
                         fminf(minb[tid][2], minb[tid][3]));
    cnt[tid] = 0;
  }
  __syncthreads();
  // survivor emission
  #pragma unroll
  for (int r = 0; r < 2; ++r) {
    #pragma unroll
    for (int g = 0; g < 4; ++g) {
      const int rowloc = rh2 * 32 + r * 16 + kb * 4 + g;
      const float thr = rowminf[rowloc] + MARGIN;
      #pragma unroll
      for (int t = 0; t < 16; ++t) {
        float dd = (rq[r][g] + bvl[t]) - 2.0f * acc[r][t][g];
        if (dd <= thr) {
          unsigned slot = atomicAdd(&cnt[rowloc], 1u);
          if (slot < CAP)
            survq[(size_t)(blockIdx.x * 64 + rowloc) * CAP + slot] =
                (unsigned)(c0 + t * 16 + ln);
        }
      }
    }
  }
  __syncthreads();
  if (tid < 64) counts[blockIdx.x * 64 + tid] = cnt[tid];
}

// ============ exact rescore: verified fp32 fmaf chain on survivors ============
// One thread per row. r reconstructed bit-exactly: fl(fl(x - c0) - c1)...
// Chain + epilogue + u64 (d,idx) min identical to rounds 1-11 (absmax 0.0).
__global__ __launch_bounds__(256) void k_exact(const float* __restrict__ x,
                                               const float* __restrict__ cb,
                                               const float* __restrict__ bv,
                                               const float* __restrict__ rowsq,
                                               const unsigned* __restrict__ survq,
                                               const unsigned* __restrict__ counts,
                                               int* __restrict__ idxh,
                                               float* __restrict__ fidx,
                                               int lvl) {
  const int row = blockIdx.x * 256 + threadIdx.x;
  const float* xr = x + (size_t)row * DIM;
  const float* cb_l = cb + (size_t)lvl * KCODES * DIM;
  const float* bv_l = bv + lvl * KCODES;
  const float* p0 = (lvl > 0) ? cb + ((size_t)0 * KCODES + idxh[0 * NROWS + row]) * DIM : nullptr;
  const float* p1 = (lvl > 1) ? cb + ((size_t)1 * KCODES + idxh[1 * NROWS + row]) * DIM : nullptr;
  const float* p2 = (lvl > 2) ? cb + ((size_t)2 * KCODES + idxh[2 * NROWS + row]) * DIM : nullptr;
  const float A = rowsq[row];
  const unsigned n = counts[row];
  const bool fb = (n > CAP);               // overflow fallback: scan all codes
  const unsigned total = fb ? KCODES : n;
  unsigned long long best = ~0ull;

  for (unsigned g = 0; g < total; g += 4) {
    unsigned code[4];
    #pragma unroll
    for (int j = 0; j < 4; ++j) {
      unsigned s = g + j;
      code[j] = fb ? ((s < KCODES) ? s : g)
                   : ((s < n) ? survq[(size_t)row * CAP + s] : survq[(size_t)row * CAP + g]);
    }
    const float* c0p = cb_l + (size_t)code[0] * DIM;
    const float* c1p = cb_l + (size_t)code[1] * DIM;
    const float* c2p = cb_l + (size_t)code[2] * DIM;
    const float* c3p = cb_l + (size_t)code[3] * DIM;
    float a0 = 0.f, a1 = 0.f, a2 = 0.f, a3 = 0.f;
    #pragma unroll 4
    for (int dv = 0; dv < DIM / 4; ++dv) {
      float4 rv = *reinterpret_cast<const float4*>(xr + dv * 4);
      if (lvl > 0) { float4 q = *reinterpret_cast<const float4*>(p0 + dv * 4);
                     rv.x -= q.x; rv.y -= q.y; rv.z -= q.z; rv.w -= q.w; }
      if (lvl > 1) { float4 q = *reinterpret_cast<const float4*>(p1 + dv * 4);
                     rv.x -= q.x; rv.y -= q.y; rv.z -= q.z; rv.w -= q.w; }
      if (lvl > 2) { float4 q = *reinterpret_cast<const float4*>(p2 + dv * 4);
                     rv.x -= q.x; rv.y -= q.y; rv.z -= q.z; rv.w -= q.w; }
      float4 v0 = *reinterpret_cast<const float4*>(c0p + dv * 4);
      float4 v1 = *reinterpret_cast<const float4*>(c1p + dv * 4);
      float4 v2 = *reinterpret_cast<const float4*>(c2p + dv * 4);
      float4 v3 = *reinterpret_cast<const float4*>(c3p + dv * 4);
      a0 = fmaf(rv.x, v0.x, a0); a0 = fmaf(rv.y, v0.y, a0);
      a0 = fmaf(rv.z, v0.z, a0); a0 = fmaf(rv.w, v0.w, a0);
      a1 = fmaf(rv.x, v1.x, a1); a1 = fmaf(rv.y, v1.y, a1);
      a1 = fmaf(rv.z, v1.z, a1); a1 = fmaf(rv.w, v1.w, a1);
      a2 = fmaf(rv.x, v2.x, a2); a2 = fmaf(rv.y, v2.y, a2);
      a2 = fmaf(rv.z, v2.z, a2); a2 = fmaf(rv.w, v2.w, a2);
      a3 = fmaf(rv.x, v3.x, a3); a3 = fmaf(rv.y, v3.y, a3);
      a3 = fmaf(rv.z, v3.z, a3); a3 = fmaf(rv.w, v3.w, a3);
    }
    const float av[4] = {a0, a1, a2, a3};
    #pragma unroll
    for (int j = 0; j < 4; ++j) {
      float t = A + bv_l[code[j]];     // fl(A + B)
      float dd = t - 2.0f * av[j];     // one rounding (2*dot exact)
      unsigned long long pk =
          ((unsigned long long)__float_as_uint(dd) << 32) | code[j];
      best = (pk < best) ? pk : best;
    }
  }
  const int id = (int)(best & 0xffffffffull);
  idxh[lvl * NROWS + row] = id;
  fidx[lvl * NROWS + row] = (float)id;
}

// ============ residual update (row-major) + quant accum + losses + next rhi ============
__global__ __launch_bounds__(256) void k_update(const float* __restrict__ x,
                                                const float* __restrict__ cb,
                                                const int* __restrict__ idxh,
                                                float* __restrict__ tq,
                                                float* __restrict__ part,
                                                float* __restrict__ rowsq,
                                                unsigned short* __restrict__ rhi,
                                                int lvl) {
  __shared__ float sred[256];
  __shared__ float rsum[16];
  const int tid = threadIdx.x;
  const int row = blockIdx.x * 16 + (tid >> 4);
  const int l16 = tid & 15;
  const size_t obase = (size_t)row * DIM + l16 * 16;

  // reconstruct residual r (bit-exact fl chain over prior levels)
  float4 rj[4];
  {
    const float4* xp = reinterpret_cast<const float4*>(x + obase);
    #pragma unroll
    for (int j = 0; j < 4; ++j) rj[j] = xp[j];
    for (int p = 0; p < lvl; ++p) {
      const float4* qp = reinterpret_cast<const float4*>(
          cb + ((size_t)p * KCODES + idxh[p * NROWS + row]) * DIM + l16 * 16);
      #pragma unroll
      for (int j = 0; j < 4; ++j) {
        float4 q = qp[j];
        rj[j].x -= q.x; rj[j].y -= q.y; rj[j].z -= q.z; rj[j].w -= q.w;
      }
    }
  }

  const int id = idxh[lvl * NROWS + row];
  const float4* cp = reinterpret_cast<const float4*>(
      cb + ((size_t)lvl * KCODES + id) * DIM + l16 * 16);
  float4* tp = reinterpret_cast<float4*>(tq + obase);
  const float4* xp = reinterpret_cast<const float4*>(x + obase);
  float nn[16];
  float e = 0.f;
  #pragma unroll
  for (int j = 0; j < 4; ++j) {
    float4 c = cp[j];
    float n0 = rj[j].x - c.x, n1 = rj[j].y - c.y;
    float n2 = rj[j].z - c.z, n3 = rj[j].w - c.w;
    nn[4 * j + 0] = n0; nn[4 * j + 1] = n1; nn[4 * j + 2] = n2; nn[4 * j + 3] = n3;
    e += (n0 * n0 + n1 * n1) + (n2 * n2 + n3 * n3);
    float4 tv;
    if (lvl == 0) {
      tv = c;
    } else {
      tv = tp[j];
      tv.x += c.x; tv.y += c.y; tv.z += c.z; tv.w += c.w;
    }
    if (lvl == 3) {
      float4 xv = xp[j];
      tv.x = xv.x + (tv.x - xv.x); tv.y = xv.y + (tv.y - xv.y);
      tv.z = xv.z + (tv.z - xv.z); tv.w = xv.w + (tv.w - xv.w);
    }
    tp[j] = tv;
  }

  if (lvl < 3) {
    unsigned w[8];
    #pragma unroll
    for (int k = 0; k < 8; ++k)
      w[k] = (unsigned)f2bf(nn[2 * k]) | ((unsigned)f2bf(nn[2 * k + 1]) << 16);
    unsigned* o = reinterpret_cast<unsigned*>(rhi + obase);
    #pragma unroll
    for (int k = 0; k < 8; ++k) o[k] = w[k];
  }

  sred[tid] = e;
  __syncthreads();
  if (tid < 16) {
    float s = 0.f;
    #pragma unroll
    for (int k = 0; k < 16; ++k) s += sred[tid * 16 + k];
    rsum[tid] = s;
    if (lvl < 3) rowsq[blockIdx.x * 16 + tid] = s;
  }
  __syncthreads();
  if (tid == 0) {
    float p = 0.f;
    #pragma unroll
    for (int k = 0; k < 16; ++k) p += rsum[k];
    part[blockIdx.x] = p;
  }
}

// ============ loss finalize (unchanged) ============
__global__ __launch_bounds__(256) void k_loss(const float* __restrict__ part,
                                              float* __restrict__ out) {
  __shared__ float s[256];
  const int tid = threadIdx.x;
  float means[4];
  for (int l = 0; l < 4; ++l) {
    float sum = 0.f;
    for (int i = tid; i < 2048; i += 256) sum += part[l * 2048 + i];
    s[tid] = sum;
    __syncthreads();
    for (int st = 128; st > 0; st >>= 1) {
      if (tid < st) s[tid] += s[tid + st];
      __syncthreads();
    }
    means[l] = s[0] * (1.0f / 8388608.0f);
    __syncthreads();
  }
  if (tid == 0) {
    float t = ((means[0] + means[1]) + means[2]) + means[3];
    float loss = t * 0.25f;
    out[0] = loss;
    out[1] = loss;
  }
}

extern "C" void kernel_launch(void* const* d_in, const int* in_sizes, int n_in,
                              void* d_out, int out_size, void* d_ws, size_t ws_size,
                              hipStream_t stream) {
  const float* x  = (const float*)d_in[0];
  const float* cb = (const float*)d_in[1];
  float* out = (float*)d_out;
  float* ws  = (float*)d_ws;

  // ws layout (float units)
  unsigned short* rhi = (unsigned short*)ws;                       // 4194304 f
  unsigned short* chi = (unsigned short*)(ws + 4194304);           // 524288 f
  unsigned* survq  = (unsigned*)(ws + 4194304 + 524288);           // 524288 f
  unsigned* counts = (unsigned*)(ws + 4194304 + 524288 + 524288);  // 32768 f
  int* idxh        = (int*)(ws + 4194304 + 524288 + 524288 + 32768);  // 131072 f
  float* bv    = ws + 4194304 + 524288 + 524288 + 32768 + 131072;  // 4096
  float* rowsq = bv + 4096;                                        // 32768
  float* part  = rowsq + 32768;                                    // 8192

  float* tq      = out;                    // total_quant accumulates in d_out
  float* lossout = out + 8388608;
  float* fidx    = out + 8388610;

  k_bnorm<<<16, 256, 0, stream>>>(cb, bv);
  k_csplit<<<256, 256, 0, stream>>>(cb, chi);
  k_prep<<<2048, 256, 0, stream>>>(x, rhi, rowsq);

  for (int l = 0; l < NLEV; ++l) {
    k_screen<<<512, 512, 0, stream>>>(rhi, chi + (size_t)l * KCODES * DIM,
                                      bv + l * KCODES, rowsq, survq, counts);
    k_exact<<<128, 256, 0, stream>>>(x, cb, bv, rowsq, survq, counts,
                                     idxh, fidx, l);
    k_update<<<2048, 256, 0, stream>>>(x, cb, idxh, tq, part + l * 2048,
                                       rowsq, rhi, l);
  }

  k_loss<<<1, 256, 0, stream>>>(part, lossout);
}

// Round 13
// 3563.388 us; speedup vs baseline: 5.3484x; 5.3484x over previous
//
#include <hip/hip_runtime.h>

#define NROWS 32768   // B*T = 16*2048
#define DIM 256
#define KCODES 1024
#define NLEV 4
#define CAP 16
#define MARGIN 8e-3f

typedef short short8v __attribute__((ext_vector_type(8)));
typedef float f32x4v  __attribute__((ext_vector_type(4)));

// bf16 round-to-nearest-even
static __device__ __forceinline__ unsigned short f2bf(float f) {
  unsigned u = __float_as_uint(f);
  unsigned lsb = (u >> 16) & 1u;
  u += 0x7fffu + lsb;
  return (unsigned short)(u >> 16);
}

// ============ codebook squared norms (unchanged, verified) ============
__global__ __launch_bounds__(256) void k_bnorm(const float* __restrict__ cb,
                                               float* __restrict__ bv) {
  int r = blockIdx.x * blockDim.x + threadIdx.x;
  if (r >= NLEV * KCODES) return;
  const float4* p = reinterpret_cast<const float4*>(cb + (size_t)r * DIM);
  float s0 = 0.f, s1 = 0.f, s2 = 0.f, s3 = 0.f;
  for (int g = 0; g < DIM / 4; ++g) {
    float4 v = p[g];
    s0 += v.x * v.x; s1 += v.y * v.y; s2 += v.z * v.z; s3 += v.w * v.w;
  }
  bv[r] = (s0 + s1) + (s2 + s3);
}

// ============ codebook -> bf16 (chi), all levels ============
__global__ __launch_bounds__(256) void k_csplit(const float* __restrict__ cb,
                                                unsigned short* __restrict__ chi) {
  const int tid = threadIdx.x;
  const int cr = blockIdx.x * 16 + (tid >> 4);  // 0..4095
  const int l16 = tid & 15;
  const float4* p = reinterpret_cast<const float4*>(cb + (size_t)cr * DIM + l16 * 16);
  unsigned w[8];
  #pragma unroll
  for (int j = 0; j < 4; ++j) {
    float4 v = p[j];
    w[2 * j + 0] = (unsigned)f2bf(v.x) | ((unsigned)f2bf(v.y) << 16);
    w[2 * j + 1] = (unsigned)f2bf(v.z) | ((unsigned)f2bf(v.w) << 16);
  }
  unsigned* o = reinterpret_cast<unsigned*>(chi + (size_t)cr * DIM + l16 * 16);
  #pragma unroll
  for (int k = 0; k < 8; ++k) o[k] = w[k];
}

// ============ x -> rowsq + rhi (bf16 of level-0 residual) ============
__global__ __launch_bounds__(256) void k_prep(const float* __restrict__ x,
                                              unsigned short* __restrict__ rhi,
                                              float* __restrict__ rowsq) {
  __shared__ float sred[256];
  const int tid = threadIdx.x;
  const int row = blockIdx.x * 16 + (tid >> 4);
  const int l16 = tid & 15;
  const float4* p = reinterpret_cast<const float4*>(x + (size_t)row * DIM + l16 * 16);
  float e = 0.f;
  unsigned w[8];
  #pragma unroll
  for (int j = 0; j < 4; ++j) {
    float4 v = p[j];
    e += v.x * v.x + v.y * v.y + v.z * v.z + v.w * v.w;
    w[2 * j + 0] = (unsigned)f2bf(v.x) | ((unsigned)f2bf(v.y) << 16);
    w[2 * j + 1] = (unsigned)f2bf(v.z) | ((unsigned)f2bf(v.w) << 16);
  }
  unsigned* o = reinterpret_cast<unsigned*>(rhi + (size_t)row * DIM + l16 * 16);
  #pragma unroll
  for (int k = 0; k < 8; ++k) o[k] = w[k];
  sred[tid] = e;
  __syncthreads();
  if (tid < 16) {
    float s = 0.f;
    #pragma unroll
    for (int k = 0; k < 16; ++k) s += sred[tid * 16 + k];
    rowsq[blockIdx.x * 16 + tid] = s;
  }
}

// ============ MFMA bf16 screen, one level (unchanged, verified r12) ============
__global__ __launch_bounds__(512) void k_screen(const unsigned short* __restrict__ rhi,
                                                const unsigned short* __restrict__ chi_l,
                                                const float* __restrict__ bv_l,
                                                const float* __restrict__ rowsq,
                                                unsigned* __restrict__ survq,
                                                unsigned* __restrict__ counts) {
  __shared__ float minb[64][4];
  __shared__ float rowminf[64];
  __shared__ unsigned cnt[64];
  const int tid = threadIdx.x;
  const int lane = tid & 63;
  const int w = tid >> 6;
  const int rh2 = w >> 2;
  const int cg = w & 3;
  const int row0 = blockIdx.x * 64 + rh2 * 32;
  const int c0 = cg * 256;
  const int ln = lane & 15;
  const int kb = lane >> 4;

  f32x4v acc[2][16];
  #pragma unroll
  for (int r = 0; r < 2; ++r)
    #pragma unroll
    for (int t = 0; t < 16; ++t) acc[r][t] = (f32x4v){0.f, 0.f, 0.f, 0.f};

  const unsigned short* aptr0 = rhi + (size_t)(row0 + ln) * DIM + kb * 8;
  const unsigned short* aptr1 = aptr0 + 16 * DIM;
  const unsigned short* bptr = chi_l + (size_t)(c0 + ln) * DIM + kb * 8;

  #pragma unroll 1
  for (int ks = 0; ks < 8; ++ks) {
    short8v a0 = *reinterpret_cast<const short8v*>(aptr0 + ks * 32);
    short8v a1 = *reinterpret_cast<const short8v*>(aptr1 + ks * 32);
    #pragma unroll
    for (int t = 0; t < 16; ++t) {
      short8v b = *reinterpret_cast<const short8v*>(bptr + (size_t)t * 16 * DIM + ks * 32);
      acc[0][t] = __builtin_amdgcn_mfma_f32_16x16x32_bf16(a0, b, acc[0][t], 0, 0, 0);
      acc[1][t] = __builtin_amdgcn_mfma_f32_16x16x32_bf16(a1, b, acc[1][t], 0, 0, 0);
    }
  }

  float bvl[16];
  #pragma unroll
  for (int t = 0; t < 16; ++t) bvl[t] = bv_l[c0 + t * 16 + ln];
  float rq[2][4];
  #pragma unroll
  for (int r = 0; r < 2; ++r)
    #pragma unroll
    for (int g = 0; g < 4; ++g) rq[r][g] = rowsq[row0 + r * 16 + kb * 4 + g];

  #pragma unroll
  for (int r = 0; r < 2; ++r) {
    #pragma unroll
    for (int g = 0; g < 4; ++g) {
      float v = __builtin_inff();
      #pragma unroll
      for (int t = 0; t < 16; ++t) {
        float dd = (rq[r][g] + bvl[t]) - 2.0f * acc[r][t][g];
        v = fminf(v, dd);
      }
      #pragma unroll
      for (int m = 1; m < 16; m <<= 1) v = fminf(v, __shfl_xor(v, m));
      if (ln == 0) minb[rh2 * 32 + r * 16 + kb * 4 + g][cg] = v;
    }
  }
  __syncthreads();
  if (tid < 64) {
    rowminf[tid] = fminf(fminf(minb[tid][0], minb[tid][1]),
                         fminf(minb[tid][2], minb[tid][3]));
    cnt[tid] = 0;
  }
  __syncthreads();
  #pragma unroll
  for (int r = 0; r < 2; ++r) {
    #pragma unroll
    for (int g = 0; g < 4; ++g) {
      const int rowloc = rh2 * 32 + r * 16 + kb * 4 + g;
      const float thr = rowminf[rowloc] + MARGIN;
      #pragma unroll
      for (int t = 0; t < 16; ++t) {
        float dd = (rq[r][g] + bvl[t]) - 2.0f * acc[r][t][g];
        if (dd <= thr) {
          unsigned slot = atomicAdd(&cnt[rowloc], 1u);
          if (slot < CAP)
            survq[(size_t)(blockIdx.x * 64 + rowloc) * CAP + slot] =
                (unsigned)(c0 + t * 16 + ln);
        }
      }
    }
  }
  __syncthreads();
  if (tid < 64) counts[blockIdx.x * 64 + tid] = cnt[tid];
}

// ============ exact rescore: verified fp32 fmaf chain on survivors ============
// Block = 16 rows; thread = (row, slot) with slot in [0,16). Each active
// thread runs the SAME ascending-d fmaf chain as rounds 1-12 for one code;
// overflow rows stripe all 1024 codes over their 16 threads. Cross-slot
// combine = u64 (dist,idx) min via 16-lane shuffles (order-independent,
// first-index ties) -> indices bit-identical to round 12 (absmax 0.0).
__global__ __launch_bounds__(256) void k_exact(const float* __restrict__ x,
                                               const float* __restrict__ cb,
                                               const float* __restrict__ bv,
                                               const float* __restrict__ rowsq,
                                               const unsigned* __restrict__ survq,
                                               const unsigned* __restrict__ counts,
                                               int* __restrict__ idxh,
                                               float* __restrict__ fidx,
                                               int lvl) {
  const int tid = threadIdx.x;
  const int row = blockIdx.x * 16 + (tid >> 4);
  const int slot = tid & 15;
  const float* xr = x + (size_t)row * DIM;
  const float* cb_l = cb + (size_t)lvl * KCODES * DIM;
  const float* bv_l = bv + lvl * KCODES;
  const float* p0 = (lvl > 0) ? cb + ((size_t)0 * KCODES + idxh[0 * NROWS + row]) * DIM : nullptr;
  const float* p1 = (lvl > 1) ? cb + ((size_t)1 * KCODES + idxh[1 * NROWS + row]) * DIM : nullptr;
  const float* p2 = (lvl > 2) ? cb + ((size_t)2 * KCODES + idxh[2 * NROWS + row]) * DIM : nullptr;
  const float A = rowsq[row];
  const unsigned n = counts[row];
  unsigned long long best = ~0ull;

#define CHAIN(CODE)                                                            \
  {                                                                            \
    const float* cp = cb_l + (size_t)(CODE)*DIM;                               \
    float a0 = 0.f;                                                            \
    _Pragma("unroll 4")                                                        \
    for (int dv = 0; dv < DIM / 4; ++dv) {                                     \
      float4 rv = *reinterpret_cast<const float4*>(xr + dv * 4);               \
      if (lvl > 0) { float4 q = *reinterpret_cast<const float4*>(p0 + dv * 4); \
                     rv.x -= q.x; rv.y -= q.y; rv.z -= q.z; rv.w -= q.w; }     \
      if (lvl > 1) { float4 q = *reinterpret_cast<const float4*>(p1 + dv * 4); \
                     rv.x -= q.x; rv.y -= q.y; rv.z -= q.z; rv.w -= q.w; }     \
      if (lvl > 2) { float4 q = *reinterpret_cast<const float4*>(p2 + dv * 4); \
                     rv.x -= q.x; rv.y -= q.y; rv.z -= q.z; rv.w -= q.w; }     \
      float4 cv = *reinterpret_cast<const float4*>(cp + dv * 4);               \
      a0 = fmaf(rv.x, cv.x, a0); a0 = fmaf(rv.y, cv.y, a0);                    \
      a0 = fmaf(rv.z, cv.z, a0); a0 = fmaf(rv.w, cv.w, a0);                    \
    }                                                                          \
    float t = A + bv_l[(CODE)];   /* fl(A + B) */                              \
    float dd = t - 2.0f * a0;     /* one rounding (2*dot exact) */             \
    unsigned long long pk =                                                    \
        ((unsigned long long)__float_as_uint(dd) << 32) | (unsigned)(CODE);    \
    best = (pk < best) ? pk : best;                                            \
  }

  if (n <= CAP) {
    if (slot < (int)n) {
      unsigned code = survq[(size_t)row * CAP + slot];
      CHAIN(code);
    }
  } else {
    // overflow fallback (P ~ 1e-11): stripe all codes over the 16 slots
    for (unsigned c = slot; c < KCODES; c += 16) CHAIN(c);
  }
#undef CHAIN

  // u64 (dist,idx) min across the row's 16 slots (lanes stay in 16-groups)
  #pragma unroll
  for (int m = 1; m < 16; m <<= 1) {
    unsigned long long o = __shfl_xor(best, m);
    best = (o < best) ? o : best;
  }
  if (slot == 0) {
    const int id = (int)(best & 0xffffffffull);
    idxh[lvl * NROWS + row] = id;
    fidx[lvl * NROWS + row] = (float)id;
  }
}

// ============ residual update + quant accum + losses + next rhi (verified r12) ============
__global__ __launch_bounds__(256) void k_update(const float* __restrict__ x,
                                                const float* __restrict__ cb,
                                                const int* __restrict__ idxh,
                                                float* __restrict__ tq,
                                                float* __restrict__ part,
                                                float* __restrict__ rowsq,
                                                unsigned short* __restrict__ rhi,
                                                int lvl) {
  __shared__ float sred[256];
  __shared__ float rsum[16];
  const int tid = threadIdx.x;
  const int row = blockIdx.x * 16 + (tid >> 4);
  const int l16 = tid & 15;
  const size_t obase = (size_t)row * DIM + l16 * 16;

  float4 rj[4];
  {
    const float4* xp = reinterpret_cast<const float4*>(x + obase);
    #pragma unroll
    for (int j = 0; j < 4; ++j) rj[j] = xp[j];
    for (int p = 0; p < lvl; ++p) {
      const float4* qp = reinterpret_cast<const float4*>(
          cb + ((size_t)p * KCODES + idxh[p * NROWS + row]) * DIM + l16 * 16);
      #pragma unroll
      for (int j = 0; j < 4; ++j) {
        float4 q = qp[j];
        rj[j].x -= q.x; rj[j].y -= q.y; rj[j].z -= q.z; rj[j].w -= q.w;
      }
    }
  }

  const int id = idxh[lvl * NROWS + row];
  const float4* cp = reinterpret_cast<const float4*>(
      cb + ((size_t)lvl * KCODES + id) * DIM + l16 * 16);
  float4* tp = reinterpret_cast<float4*>(tq + obase);
  const float4* xp = reinterpret_cast<const float4*>(x + obase);
  float nn[16];
  float e = 0.f;
  #pragma unroll
  for (int j = 0; j < 4; ++j) {
    float4 c = cp[j];
    float n0 = rj[j].x - c.x, n1 = rj[j].y - c.y;
    float n2 = rj[j].z - c.z, n3 = rj[j].w - c.w;
    nn[4 * j + 0] = n0; nn[4 * j + 1] = n1; nn[4 * j + 2] = n2; nn[4 * j + 3] = n3;
    e += (n0 * n0 + n1 * n1) + (n2 * n2 + n3 * n3);
    float4 tv;
    if (lvl == 0) {
      tv = c;
    } else {
      tv = tp[j];
      tv.x += c.x; tv.y += c.y; tv.z += c.z; tv.w += c.w;
    }
    if (lvl == 3) {
      float4 xv = xp[j];
      tv.x = xv.x + (tv.x - xv.x); tv.y = xv.y + (tv.y - xv.y);
      tv.z = xv.z + (tv.z - xv.z); tv.w = xv.w + (tv.w - xv.w);
    }
    tp[j] = tv;
  }

  if (lvl < 3) {
    unsigned w[8];
    #pragma unroll
    for (int k = 0; k < 8; ++k)
      w[k] = (unsigned)f2bf(nn[2 * k]) | ((unsigned)f2bf(nn[2 * k + 1]) << 16);
    unsigned* o = reinterpret_cast<unsigned*>(rhi + obase);
    #pragma unroll
    for (int k = 0; k < 8; ++k) o[k] = w[k];
  }

  sred[tid] = e;
  __syncthreads();
  if (tid < 16) {
    float s = 0.f;
    #pragma unroll
    for (int k = 0; k < 16; ++k) s += sred[tid * 16 + k];
    rsum[tid] = s;
    if (lvl < 3) rowsq[blockIdx.x * 16 + tid] = s;
  }
  __syncthreads();
  if (tid == 0) {
    float p = 0.f;
    #pragma unroll
    for (int k = 0; k < 16; ++k) p += rsum[k];
    part[blockIdx.x] = p;
  }
}

// ============ loss finalize (unchanged) ============
__global__ __launch_bounds__(256) void k_loss(const float* __restrict__ part,
                                              float* __restrict__ out) {
  __shared__ float s[256];
  const int tid = threadIdx.x;
  float means[4];
  for (int l = 0; l < 4; ++l) {
    float sum = 0.f;
    for (int i = tid; i < 2048; i += 256) sum += part[l * 2048 + i];
    s[tid] = sum;
    __syncthreads();
    for (int st = 128; st > 0; st >>= 1) {
      if (tid < st) s[tid] += s[tid + st];
      __syncthreads();
    }
    means[l] = s[0] * (1.0f / 8388608.0f);
    __syncthreads();
  }
  if (tid == 0) {
    float t = ((means[0] + means[1]) + means[2]) + means[3];
    float loss = t * 0.25f;
    out[0] = loss;
    out[1] = loss;
  }
}

extern "C" void kernel_launch(void* const* d_in, const int* in_sizes, int n_in,
                              void* d_out, int out_size, void* d_ws, size_t ws_size,
                              hipStream_t stream) {
  const float* x  = (const float*)d_in[0];
  const float* cb = (const float*)d_in[1];
  float* out = (float*)d_out;
  float* ws  = (float*)d_ws;

  // ws layout (float units)
  unsigned short* rhi = (unsigned short*)ws;                       // 4194304 f
  unsigned short* chi = (unsigned short*)(ws + 4194304);           // 524288 f
  unsigned* survq  = (unsigned*)(ws + 4194304 + 524288);           // 524288 f
  unsigned* counts = (unsigned*)(ws + 4194304 + 524288 + 524288);  // 32768 f
  int* idxh        = (int*)(ws + 4194304 + 524288 + 524288 + 32768);  // 131072 f
  float* bv    = ws + 4194304 + 524288 + 524288 + 32768 + 131072;  // 4096
  float* rowsq = bv + 4096;                                        // 32768
  float* part  = rowsq + 32768;                                    // 8192

  float* tq      = out;                    // total_quant accumulates in d_out
  float* lossout = out + 8388608;
  float* fidx    = out + 8388610;

  k_bnorm<<<16, 256, 0, stream>>>(cb, bv);
  k_csplit<<<256, 256, 0, stream>>>(cb, chi);
  k_prep<<<2048, 256, 0, stream>>>(x, rhi, rowsq);

  for (int l = 0; l < NLEV; ++l) {
    k_screen<<<512, 512, 0, stream>>>(rhi, chi + (size_t)l * KCODES * DIM,
                                      bv + l * KCODES, rowsq, survq, counts);
    k_exact<<<2048, 256, 0, stream>>>(x, cb, bv, rowsq, survq, counts,
                                      idxh, fidx, l);
    k_update<<<2048, 256, 0, stream>>>(x, cb, idxh, tq, part + l * 2048,
                                       rowsq, rhi, l);
  }

  k_loss<<<1, 256, 0, stream>>>(part, lossout);
}

// Round 14
// 572.484 us; speedup vs baseline: 33.2906x; 6.2244x over previous
//
#include <hip/hip_runtime.h>

#define NROWS 32768   // B*T = 16*2048
#define DIM 256
#define KCODES 1024
#define NLEV 4
#define CAP 64
#define MARGIN 8e-3f

typedef short short8v __attribute__((ext_vector_type(8)));
typedef float f32x4v  __attribute__((ext_vector_type(4)));

// bf16 round-to-nearest-even
static __device__ __forceinline__ unsigned short f2bf(float f) {
  unsigned u = __float_as_uint(f);
  unsigned lsb = (u >> 16) & 1u;
  u += 0x7fffu + lsb;
  return (unsigned short)(u >> 16);
}

// ============ codebook squared norms (unchanged, verified) ============
__global__ __launch_bounds__(256) void k_bnorm(const float* __restrict__ cb,
                                               float* __restrict__ bv) {
  int r = blockIdx.x * blockDim.x + threadIdx.x;
  if (r >= NLEV * KCODES) return;
  const float4* p = reinterpret_cast<const float4*>(cb + (size_t)r * DIM);
  float s0 = 0.f, s1 = 0.f, s2 = 0.f, s3 = 0.f;
  for (int g = 0; g < DIM / 4; ++g) {
    float4 v = p[g];
    s0 += v.x * v.x; s1 += v.y * v.y; s2 += v.z * v.z; s3 += v.w * v.w;
  }
  bv[r] = (s0 + s1) + (s2 + s3);
}

// ============ codebook -> bf16 (chi), all levels (verified) ============
__global__ __launch_bounds__(256) void k_csplit(const float* __restrict__ cb,
                                                unsigned short* __restrict__ chi) {
  const int tid = threadIdx.x;
  const int cr = blockIdx.x * 16 + (tid >> 4);
  const int l16 = tid & 15;
  const float4* p = reinterpret_cast<const float4*>(cb + (size_t)cr * DIM + l16 * 16);
  unsigned w[8];
  #pragma unroll
  for (int j = 0; j < 4; ++j) {
    float4 v = p[j];
    w[2 * j + 0] = (unsigned)f2bf(v.x) | ((unsigned)f2bf(v.y) << 16);
    w[2 * j + 1] = (unsigned)f2bf(v.z) | ((unsigned)f2bf(v.w) << 16);
  }
  unsigned* o = reinterpret_cast<unsigned*>(chi + (size_t)cr * DIM + l16 * 16);
  #pragma unroll
  for (int k = 0; k < 8; ++k) o[k] = w[k];
}

// ============ x -> rowsq + rhi (verified) ============
__global__ __launch_bounds__(256) void k_prep(const float* __restrict__ x,
                                              unsigned short* __restrict__ rhi,
                                              float* __restrict__ rowsq) {
  __shared__ float sred[256];
  const int tid = threadIdx.x;
  const int row = blockIdx.x * 16 + (tid >> 4);
  const int l16 = tid & 15;
  const float4* p = reinterpret_cast<const float4*>(x + (size_t)row * DIM + l16 * 16);
  float e = 0.f;
  unsigned w[8];
  #pragma unroll
  for (int j = 0; j < 4; ++j) {
    float4 v = p[j];
    e += v.x * v.x + v.y * v.y + v.z * v.z + v.w * v.w;
    w[2 * j + 0] = (unsigned)f2bf(v.x) | ((unsigned)f2bf(v.y) << 16);
    w[2 * j + 1] = (unsigned)f2bf(v.z) | ((unsigned)f2bf(v.w) << 16);
  }
  unsigned* o = reinterpret_cast<unsigned*>(rhi + (size_t)row * DIM + l16 * 16);
  #pragma unroll
  for (int k = 0; k < 8; ++k) o[k] = w[k];
  sred[tid] = e;
  __syncthreads();
  if (tid < 16) {
    float s = 0.f;
    #pragma unroll
    for (int k = 0; k < 16; ++k) s += sred[tid * 16 + k];
    rowsq[blockIdx.x * 16 + tid] = s;
  }
}

// ============ MFMA bf16 screen, one level (verified r12/r13; CAP now 64) ============
__global__ __launch_bounds__(512) void k_screen(const unsigned short* __restrict__ rhi,
                                                const unsigned short* __restrict__ chi_l,
                                                const float* __restrict__ bv_l,
                                                const float* __restrict__ rowsq,
                                                unsigned* __restrict__ survq,
                                                unsigned* __restrict__ counts) {
  __shared__ float minb[64][4];
  __shared__ float rowminf[64];
  __shared__ unsigned cnt[64];
  const int tid = threadIdx.x;
  const int lane = tid & 63;
  const int w = tid >> 6;
  const int rh2 = w >> 2;
  const int cg = w & 3;
  const int row0 = blockIdx.x * 64 + rh2 * 32;
  const int c0 = cg * 256;
  const int ln = lane & 15;
  const int kb = lane >> 4;

  f32x4v acc[2][16];
  #pragma unroll
  for (int r = 0; r < 2; ++r)
    #pragma unroll
    for (int t = 0; t < 16; ++t) acc[r][t] = (f32x4v){0.f, 0.f, 0.f, 0.f};

  const unsigned short* aptr0 = rhi + (size_t)(row0 + ln) * DIM + kb * 8;
  const unsigned short* aptr1 = aptr0 + 16 * DIM;
  const unsigned short* bptr = chi_l + (size_t)(c0 + ln) * DIM + kb * 8;

  #pragma unroll 1
  for (int ks = 0; ks < 8; ++ks) {
    short8v a0 = *reinterpret_cast<const short8v*>(aptr0 + ks * 32);
    short8v a1 = *reinterpret_cast<const short8v*>(aptr1 + ks * 32);
    #pragma unroll
    for (int t = 0; t < 16; ++t) {
      short8v b = *reinterpret_cast<const short8v*>(bptr + (size_t)t * 16 * DIM + ks * 32);
      acc[0][t] = __builtin_amdgcn_mfma_f32_16x16x32_bf16(a0, b, acc[0][t], 0, 0, 0);
      acc[1][t] = __builtin_amdgcn_mfma_f32_16x16x32_bf16(a1, b, acc[1][t], 0, 0, 0);
    }
  }

  float bvl[16];
  #pragma unroll
  for (int t = 0; t < 16; ++t) bvl[t] = bv_l[c0 + t * 16 + ln];
  float rq[2][4];
  #pragma unroll
  for (int r = 0; r < 2; ++r)
    #pragma unroll
    for (int g = 0; g < 4; ++g) rq[r][g] = rowsq[row0 + r * 16 + kb * 4 + g];

  #pragma unroll
  for (int r = 0; r < 2; ++r) {
    #pragma unroll
    for (int g = 0; g < 4; ++g) {
      float v = __builtin_inff();
      #pragma unroll
      for (int t = 0; t < 16; ++t) {
        float dd = (rq[r][g] + bvl[t]) - 2.0f * acc[r][t][g];
        v = fminf(v, dd);
      }
      #pragma unroll
      for (int m = 1; m < 16; m <<= 1) v = fminf(v, __shfl_xor(v, m));
      if (ln == 0) minb[rh2 * 32 + r * 16 + kb * 4 + g][cg] = v;
    }
  }
  __syncthreads();
  if (tid < 64) {
    rowminf[tid] = fminf(fminf(minb[tid][0], minb[tid][1]),
                         fminf(minb[tid][2], minb[tid][3]));
    cnt[tid] = 0;
  }
  __syncthreads();
  #pragma unroll
  for (int r = 0; r < 2; ++r) {
    #pragma unroll
    for (int g = 0; g < 4; ++g) {
      const int rowloc = rh2 * 32 + r * 16 + kb * 4 + g;
      const float thr = rowminf[rowloc] + MARGIN;
      #pragma unroll
      for (int t = 0; t < 16; ++t) {
        float dd = (rq[r][g] + bvl[t]) - 2.0f * acc[r][t][g];
        if (dd <= thr) {
          unsigned slot = atomicAdd(&cnt[rowloc], 1u);
          if (slot < CAP)
            survq[(size_t)(blockIdx.x * 64 + rowloc) * CAP + slot] =
                (unsigned)(c0 + t * 16 + ln);
        }
      }
    }
  }
  __syncthreads();
  if (tid < 64) counts[blockIdx.x * 64 + tid] = cnt[tid];
}

// ============ fused exact rescore + residual update ============
// Block = 16 rows x 16 slots. Phase A: reconstruct residual via the verified
// fl chain x - c0 - c1 - ... into LDS (and registers). Phase B: each slot runs
// the verified ascending-d fmaf chain for its survivor codes (slots stride 16
// over up to CAP=64 survivors; >CAP -> full 1024 stripe, ~never). r from LDS
// (broadcast b128), code row from L2. u64 (d,idx) 16-lane min = first-index
// ties. Phase C: k_update's verified math inline (id via LDS), writing tq,
// rhi, rowsq, loss partials. Indices/distances bit-identical to rounds 12-13.
__global__ __launch_bounds__(256) void k_exupd(const float* __restrict__ x,
                                               const float* __restrict__ cb,
                                               const float* __restrict__ bv,
                                               const float* __restrict__ rowsq,
                                               const unsigned* __restrict__ survq,
                                               const unsigned* __restrict__ counts,
                                               int* __restrict__ idxh,
                                               float* __restrict__ fidx,
                                               float* __restrict__ tq,
                                               float* __restrict__ part,
                                               float* __restrict__ rowsq_o,
                                               unsigned short* __restrict__ rhi,
                                               int lvl) {
  __shared__ __align__(16) float rlds[16][260];
  __shared__ int idsh[16];
  __shared__ float sred[256];
  __shared__ float rsum[16];

  const int tid = threadIdx.x;
  const int rr = tid >> 4;     // row-in-block (phase A/C) and chain row (phase B)
  const int l16 = tid & 15;    // d-chunk (A/C), slot (B)
  const int row = blockIdx.x * 16 + rr;
  const size_t obase = (size_t)row * DIM + l16 * 16;
  const float* cb_l = cb + (size_t)lvl * KCODES * DIM;
  const float* bv_l = bv + lvl * KCODES;

  // ---- phase A: residual via verified fl chain; stage row in LDS ----
  float4 xj[4], rj[4];
  {
    const float4* xp = reinterpret_cast<const float4*>(x + obase);
    #pragma unroll
    for (int j = 0; j < 4; ++j) { xj[j] = xp[j]; rj[j] = xj[j]; }
    for (int p = 0; p < lvl; ++p) {
      const float4* qp = reinterpret_cast<const float4*>(
          cb + ((size_t)p * KCODES + idxh[p * NROWS + row]) * DIM + l16 * 16);
      #pragma unroll
      for (int j = 0; j < 4; ++j) {
        float4 q = qp[j];
        rj[j].x -= q.x; rj[j].y -= q.y; rj[j].z -= q.z; rj[j].w -= q.w;
      }
    }
    #pragma unroll
    for (int j = 0; j < 4; ++j)
      *reinterpret_cast<float4*>(&rlds[rr][l16 * 16 + 4 * j]) = rj[j];
  }
  __syncthreads();

  // ---- phase B: exact chains on survivors ----
  const float A = rowsq[row];
  const unsigned n = counts[row];
  unsigned long long best = ~0ull;

#define CHAIN(CODE)                                                            \
  {                                                                            \
    const float* cp2 = cb_l + (size_t)(CODE) * DIM;                            \
    float a0 = 0.f;                                                            \
    _Pragma("unroll 8")                                                        \
    for (int dv = 0; dv < DIM / 4; ++dv) {                                     \
      float4 rv = *reinterpret_cast<const float4*>(&rlds[rr][dv * 4]);         \
      float4 cv = *reinterpret_cast<const float4*>(cp2 + dv * 4);              \
      a0 = fmaf(rv.x, cv.x, a0); a0 = fmaf(rv.y, cv.y, a0);                    \
      a0 = fmaf(rv.z, cv.z, a0); a0 = fmaf(rv.w, cv.w, a0);                    \
    }                                                                          \
    float t = A + bv_l[(CODE)];   /* fl(A + B) */                              \
    float dd = t - 2.0f * a0;     /* one rounding (2*dot exact) */             \
    unsigned long long pk =                                                    \
        ((unsigned long long)__float_as_uint(dd) << 32) | (unsigned)(CODE);    \
    best = (pk < best) ? pk : best;                                            \
  }

  if (n <= CAP) {
    for (unsigned s = l16; s < n; s += 16) {
      unsigned code = survq[(size_t)row * CAP + s];
      CHAIN(code);
    }
  } else {
    for (unsigned c = l16; c < KCODES; c += 16) CHAIN(c);  // safety net
  }
#undef CHAIN

  #pragma unroll
  for (int m = 1; m < 16; m <<= 1) {
    unsigned long long o = __shfl_xor(best, m);
    best = (o < best) ? o : best;
  }
  if (l16 == 0) {
    const int id = (int)(best & 0xffffffffull);
    idxh[lvl * NROWS + row] = id;
    fidx[lvl * NROWS + row] = (float)id;
    idsh[rr] = id;
  }
  __syncthreads();

  // ---- phase C: verified k_update math inline ----
  const int id = idsh[rr];
  const float4* cpc = reinterpret_cast<const float4*>(
      cb_l + (size_t)id * DIM + l16 * 16);
  float4* tp = reinterpret_cast<float4*>(tq + obase);
  float nn[16];
  float e = 0.f;
  #pragma unroll
  for (int j = 0; j < 4; ++j) {
    float4 c = cpc[j];
    float n0 = rj[j].x - c.x, n1 = rj[j].y - c.y;
    float n2 = rj[j].z - c.z, n3 = rj[j].w - c.w;
    nn[4 * j + 0] = n0; nn[4 * j + 1] = n1; nn[4 * j + 2] = n2; nn[4 * j + 3] = n3;
    e += (n0 * n0 + n1 * n1) + (n2 * n2 + n3 * n3);
    float4 tv;
    if (lvl == 0) {
      tv = c;
    } else {
      tv = tp[j];
      tv.x += c.x; tv.y += c.y; tv.z += c.z; tv.w += c.w;
    }
    if (lvl == 3) {
      tv.x = xj[j].x + (tv.x - xj[j].x); tv.y = xj[j].y + (tv.y - xj[j].y);
      tv.z = xj[j].z + (tv.z - xj[j].z); tv.w = xj[j].w + (tv.w - xj[j].w);
    }
    tp[j] = tv;
  }

  if (lvl < 3) {
    unsigned w[8];
    #pragma unroll
    for (int k = 0; k < 8; ++k)
      w[k] = (unsigned)f2bf(nn[2 * k]) | ((unsigned)f2bf(nn[2 * k + 1]) << 16);
    unsigned* o = reinterpret_cast<unsigned*>(rhi + obase);
    #pragma unroll
    for (int k = 0; k < 8; ++k) o[k] = w[k];
  }

  sred[tid] = e;
  __syncthreads();
  if (tid < 16) {
    float s = 0.f;
    #pragma unroll
    for (int k = 0; k < 16; ++k) s += sred[tid * 16 + k];
    rsum[tid] = s;
    if (lvl < 3) rowsq_o[blockIdx.x * 16 + tid] = s;
  }
  __syncthreads();
  if (tid == 0) {
    float p = 0.f;
    #pragma unroll
    for (int k = 0; k < 16; ++k) p += rsum[k];
    part[blockIdx.x] = p;
  }
}

// ============ loss finalize (unchanged) ============
__global__ __launch_bounds__(256) void k_loss(const float* __restrict__ part,
                                              float* __restrict__ out) {
  __shared__ float s[256];
  const int tid = threadIdx.x;
  float means[4];
  for (int l = 0; l < 4; ++l) {
    float sum = 0.f;
    for (int i = tid; i < 2048; i += 256) sum += part[l * 2048 + i];
    s[tid] = sum;
    __syncthreads();
    for (int st = 128; st > 0; st >>= 1) {
      if (tid < st) s[tid] += s[tid + st];
      __syncthreads();
    }
    means[l] = s[0] * (1.0f / 8388608.0f);
    __syncthreads();
  }
  if (tid == 0) {
    float t = ((means[0] + means[1]) + means[2]) + means[3];
    float loss = t * 0.25f;
    out[0] = loss;
    out[1] = loss;
  }
}

extern "C" void kernel_launch(void* const* d_in, const int* in_sizes, int n_in,
                              void* d_out, int out_size, void* d_ws, size_t ws_size,
                              hipStream_t stream) {
  const float* x  = (const float*)d_in[0];
  const float* cb = (const float*)d_in[1];
  float* out = (float*)d_out;
  float* ws  = (float*)d_ws;

  // ws layout (float units)
  unsigned short* rhi = (unsigned short*)ws;                         // 4194304 f
  unsigned short* chi = (unsigned short*)(ws + 4194304);             // 524288 f
  unsigned* survq  = (unsigned*)(ws + 4194304 + 524288);             // 2097152 f (32768*64 u32)
  unsigned* counts = (unsigned*)(ws + 4194304 + 524288 + 2097152);   // 32768 f
  int* idxh        = (int*)(ws + 4194304 + 524288 + 2097152 + 32768);  // 131072 f
  float* bv    = ws + 4194304 + 524288 + 2097152 + 32768 + 131072;   // 4096
  float* rowsq = bv + 4096;                                          // 32768
  float* part  = rowsq + 32768;                                      // 8192

  float* tq      = out;                    // total_quant accumulates in d_out
  float* lossout = out + 8388608;
  float* fidx    = out + 8388610;

  k_bnorm<<<16, 256, 0, stream>>>(cb, bv);
  k_csplit<<<256, 256, 0, stream>>>(cb, chi);
  k_prep<<<2048, 256, 0, stream>>>(x, rhi, rowsq);

  for (int l = 0; l < NLEV; ++l) {
    k_screen<<<512, 512, 0, stream>>>(rhi, chi + (size_t)l * KCODES * DIM,
                                      bv + l * KCODES, rowsq, survq, counts);
    k_exupd<<<2048, 256, 0, stream>>>(x, cb, bv, rowsq, survq, counts,
                                      idxh, fidx, tq, part + l * 2048,
                                      rowsq, rhi, l);
  }

  k_loss<<<1, 256, 0, stream>>>(part, lossout);
}

// Round 15
// 502.856 us; speedup vs baseline: 37.9002x; 1.1385x over previous
//
#include <hip/hip_runtime.h>

#define NROWS 32768   // B*T = 16*2048
#define DIM 256
#define KCODES 1024
#define NLEV 4
#define CAP 64
#define MARGIN 8e-3f

typedef short short8v __attribute__((ext_vector_type(8)));
typedef float f32x4v  __attribute__((ext_vector_type(4)));

// bf16 round-to-nearest-even
static __device__ __forceinline__ unsigned short f2bf(float f) {
  unsigned u = __float_as_uint(f);
  unsigned lsb = (u >> 16) & 1u;
  u += 0x7fffu + lsb;
  return (unsigned short)(u >> 16);
}

// Packed fragment layout (per 16-row/16-code tile of 256 dims = 4096 shorts):
//   pak[tile][ks*512 + kb*128 + r8*8 + j] = elem(row = tile*16 + r8,
//                                               k = ks*32 + kb*8 + j)
// A wave reads short8v at pak + tile*4096 + ks*512 + lane*8  (lane = r8|kb<<4)
// -> contiguous 1 KB per wave instruction; fragments bit-identical to the
// verified round-12/13/14 screen.

// ============ codebook squared norms (unchanged, verified) ============
__global__ __launch_bounds__(256) void k_bnorm(const float* __restrict__ cb,
                                               float* __restrict__ bv) {
  int r = blockIdx.x * blockDim.x + threadIdx.x;
  if (r >= NLEV * KCODES) return;
  const float4* p = reinterpret_cast<const float4*>(cb + (size_t)r * DIM);
  float s0 = 0.f, s1 = 0.f, s2 = 0.f, s3 = 0.f;
  for (int g = 0; g < DIM / 4; ++g) {
    float4 v = p[g];
    s0 += v.x * v.x; s1 += v.y * v.y; s2 += v.z * v.z; s3 += v.w * v.w;
  }
  bv[r] = (s0 + s1) + (s2 + s3);
}

// ============ codebook -> bf16, PACKED fragment layout ============
__global__ __launch_bounds__(256) void k_csplit(const float* __restrict__ cb,
                                                unsigned short* __restrict__ chi) {
  const int tid = threadIdx.x;
  const int cr = blockIdx.x * 16 + (tid >> 4);  // global code row 0..4095
  const int l16 = tid & 15;
  const float4* p = reinterpret_cast<const float4*>(cb + (size_t)cr * DIM + l16 * 16);
  unsigned w[8];
  #pragma unroll
  for (int j = 0; j < 4; ++j) {
    float4 v = p[j];
    w[2 * j + 0] = (unsigned)f2bf(v.x) | ((unsigned)f2bf(v.y) << 16);
    w[2 * j + 1] = (unsigned)f2bf(v.z) | ((unsigned)f2bf(v.w) << 16);
  }
  const int lvl_ = cr >> 10;
  const int c = cr & 1023;
  unsigned short* base = chi + (size_t)lvl_ * (KCODES * DIM) + (size_t)(c >> 4) * 4096;
  const int c8 = c & 15;
  const int ks = l16 >> 1;
  const int kb0 = (l16 & 1) * 2;
  *reinterpret_cast<uint4*>(base + ks * 512 + kb0 * 128 + c8 * 8) =
      make_uint4(w[0], w[1], w[2], w[3]);
  *reinterpret_cast<uint4*>(base + ks * 512 + (kb0 + 1) * 128 + c8 * 8) =
      make_uint4(w[4], w[5], w[6], w[7]);
}

// ============ x -> rowsq + rhi (PACKED) ============
__global__ __launch_bounds__(256) void k_prep(const float* __restrict__ x,
                                              unsigned short* __restrict__ rhi,
                                              float* __restrict__ rowsq) {
  __shared__ float sred[256];
  const int tid = threadIdx.x;
  const int rr = tid >> 4;
  const int l16 = tid & 15;
  const int row = blockIdx.x * 16 + rr;
  const float4* p = reinterpret_cast<const float4*>(x + (size_t)row * DIM + l16 * 16);
  float e = 0.f;
  unsigned w[8];
  #pragma unroll
  for (int j = 0; j < 4; ++j) {
    float4 v = p[j];
    e += v.x * v.x + v.y * v.y + v.z * v.z + v.w * v.w;
    w[2 * j + 0] = (unsigned)f2bf(v.x) | ((unsigned)f2bf(v.y) << 16);
    w[2 * j + 1] = (unsigned)f2bf(v.z) | ((unsigned)f2bf(v.w) << 16);
  }
  unsigned short* base = rhi + (size_t)blockIdx.x * 4096;
  const int ks = l16 >> 1;
  const int kb0 = (l16 & 1) * 2;
  *reinterpret_cast<uint4*>(base + ks * 512 + kb0 * 128 + rr * 8) =
      make_uint4(w[0], w[1], w[2], w[3]);
  *reinterpret_cast<uint4*>(base + ks * 512 + (kb0 + 1) * 128 + rr * 8) =
      make_uint4(w[4], w[5], w[6], w[7]);
  sred[tid] = e;
  __syncthreads();
  if (tid < 16) {
    float s = 0.f;
    #pragma unroll
    for (int k = 0; k < 16; ++k) s += sred[tid * 16 + k];
    rowsq[blockIdx.x * 16 + tid] = s;
  }
}

// ============ MFMA bf16 screen, one level (packed-coalesced loads) ============
__global__ __launch_bounds__(512) void k_screen(const unsigned short* __restrict__ rhi,
                                                const unsigned short* __restrict__ chi_l,
                                                const float* __restrict__ bv_l,
                                                const float* __restrict__ rowsq,
                                                unsigned* __restrict__ survq,
                                                unsigned* __restrict__ counts) {
  __shared__ float minb[64][4];
  __shared__ float rowminf[64];
  __shared__ unsigned cnt[64];
  const int tid = threadIdx.x;
  const int lane = tid & 63;
  const int w = tid >> 6;
  const int rh2 = w >> 2;
  const int cg = w & 3;
  const int row0 = blockIdx.x * 64 + rh2 * 32;
  const int c0 = cg * 256;
  const int ln = lane & 15;
  const int kb = lane >> 4;

  f32x4v acc[2][16];
  #pragma unroll
  for (int r = 0; r < 2; ++r)
    #pragma unroll
    for (int t = 0; t < 16; ++t) acc[r][t] = (f32x4v){0.f, 0.f, 0.f, 0.f};

  // packed bases: A tiles rt0, rt0+1; B tiles (c0>>4)+t. All loads contiguous.
  const unsigned short* pa = rhi + (size_t)(blockIdx.x * 4 + rh2 * 2) * 4096 + lane * 8;
  const unsigned short* pb = chi_l + (size_t)(c0 >> 4) * 4096 + lane * 8;

  #pragma unroll 1
  for (int ks = 0; ks < 8; ++ks) {
    short8v a0 = *reinterpret_cast<const short8v*>(pa + ks * 512);
    short8v a1 = *reinterpret_cast<const short8v*>(pa + 4096 + ks * 512);
    #pragma unroll
    for (int t = 0; t < 16; ++t) {
      short8v b = *reinterpret_cast<const short8v*>(pb + t * 4096 + ks * 512);
      acc[0][t] = __builtin_amdgcn_mfma_f32_16x16x32_bf16(a0, b, acc[0][t], 0, 0, 0);
      acc[1][t] = __builtin_amdgcn_mfma_f32_16x16x32_bf16(a1, b, acc[1][t], 0, 0, 0);
    }
  }

  float bvl[16];
  #pragma unroll
  for (int t = 0; t < 16; ++t) bvl[t] = bv_l[c0 + t * 16 + ln];
  float rq[2][4];
  #pragma unroll
  for (int r = 0; r < 2; ++r)
    #pragma unroll
    for (int g = 0; g < 4; ++g) rq[r][g] = rowsq[row0 + r * 16 + kb * 4 + g];

  #pragma unroll
  for (int r = 0; r < 2; ++r) {
    #pragma unroll
    for (int g = 0; g < 4; ++g) {
      float v = __builtin_inff();
      #pragma unroll
      for (int t = 0; t < 16; ++t) {
        float dd = (rq[r][g] + bvl[t]) - 2.0f * acc[r][t][g];
        v = fminf(v, dd);
      }
      #pragma unroll
      for (int m = 1; m < 16; m <<= 1) v = fminf(v, __shfl_xor(v, m));
      if (ln == 0) minb[rh2 * 32 + r * 16 + kb * 4 + g][cg] = v;
    }
  }
  __syncthreads();
  if (tid < 64) {
    rowminf[tid] = fminf(fminf(minb[tid][0], minb[tid][1]),
                         fminf(minb[tid][2], minb[tid][3]));
    cnt[tid] = 0;
  }
  __syncthreads();
  #pragma unroll
  for (int r = 0; r < 2; ++r) {
    #pragma unroll
    for (int g = 0; g < 4; ++g) {
      const int rowloc = rh2 * 32 + r * 16 + kb * 4 + g;
      const float thr = rowminf[rowloc] + MARGIN;
      #pragma unroll
      for (int t = 0; t < 16; ++t) {
        float dd = (rq[r][g] + bvl[t]) - 2.0f * acc[r][t][g];
        if (dd <= thr) {
          unsigned slot = atomicAdd(&cnt[rowloc], 1u);
          if (slot < CAP)
            survq[(size_t)(blockIdx.x * 64 + rowloc) * CAP + slot] =
                (unsigned)(c0 + t * 16 + ln);
        }
      }
    }
  }
  __syncthreads();
  if (tid < 64) counts[blockIdx.x * 64 + tid] = cnt[tid];
}

// ============ fused exact rescore + residual update (verified r14) ============
__global__ __launch_bounds__(256) void k_exupd(const float* __restrict__ x,
                                               const float* __restrict__ cb,
                                               const float* __restrict__ bv,
                                               const float* __restrict__ rowsq,
                                               const unsigned* __restrict__ survq,
                                               const unsigned* __restrict__ counts,
                                               int* __restrict__ idxh,
                                               float* __restrict__ fidx,
                                               float* __restrict__ tq,
                                               float* __restrict__ part,
                                               float* __restrict__ rowsq_o,
                                               unsigned short* __restrict__ rhi,
                                               int lvl) {
  __shared__ __align__(16) float rlds[16][260];
  __shared__ int idsh[16];
  __shared__ float sred[256];
  __shared__ float rsum[16];

  const int tid = threadIdx.x;
  const int rr = tid >> 4;
  const int l16 = tid & 15;
  const int row = blockIdx.x * 16 + rr;
  const size_t obase = (size_t)row * DIM + l16 * 16;
  const float* cb_l = cb + (size_t)lvl * KCODES * DIM;
  const float* bv_l = bv + lvl * KCODES;

  // ---- phase A: residual via verified fl chain; stage row in LDS ----
  float4 xj[4], rj[4];
  {
    const float4* xp = reinterpret_cast<const float4*>(x + obase);
    #pragma unroll
    for (int j = 0; j < 4; ++j) { xj[j] = xp[j]; rj[j] = xj[j]; }
    for (int p = 0; p < lvl; ++p) {
      const float4* qp = reinterpret_cast<const float4*>(
          cb + ((size_t)p * KCODES + idxh[p * NROWS + row]) * DIM + l16 * 16);
      #pragma unroll
      for (int j = 0; j < 4; ++j) {
        float4 q = qp[j];
        rj[j].x -= q.x; rj[j].y -= q.y; rj[j].z -= q.z; rj[j].w -= q.w;
      }
    }
    #pragma unroll
    for (int j = 0; j < 4; ++j)
      *reinterpret_cast<float4*>(&rlds[rr][l16 * 16 + 4 * j]) = rj[j];
  }
  __syncthreads();

  // ---- phase B: exact chains on survivors ----
  const float A = rowsq[row];
  const unsigned n = counts[row];
  unsigned long long best = ~0ull;

#define CHAIN(CODE)                                                            \
  {                                                                            \
    const float* cp2 = cb_l + (size_t)(CODE) * DIM;                            \
    float a0 = 0.f;                                                            \
    _Pragma("unroll 8")                                                        \
    for (int dv = 0; dv < DIM / 4; ++dv) {                                     \
      float4 rv = *reinterpret_cast<const float4*>(&rlds[rr][dv * 4]);         \
      float4 cv = *reinterpret_cast<const float4*>(cp2 + dv * 4);              \
      a0 = fmaf(rv.x, cv.x, a0); a0 = fmaf(rv.y, cv.y, a0);                    \
      a0 = fmaf(rv.z, cv.z, a0); a0 = fmaf(rv.w, cv.w, a0);                    \
    }                                                                          \
    float t = A + bv_l[(CODE)];   /* fl(A + B) */                              \
    float dd = t - 2.0f * a0;     /* one rounding (2*dot exact) */             \
    unsigned long long pk =                                                    \
        ((unsigned long long)__float_as_uint(dd) << 32) | (unsigned)(CODE);    \
    best = (pk < best) ? pk : best;                                            \
  }

  if (n <= CAP) {
    for (unsigned s = l16; s < n; s += 16) {
      unsigned code = survq[(size_t)row * CAP + s];
      CHAIN(code);
    }
  } else {
    for (unsigned c = l16; c < KCODES; c += 16) CHAIN(c);  // safety net
  }
#undef CHAIN

  #pragma unroll
  for (int m = 1; m < 16; m <<= 1) {
    unsigned long long o = __shfl_xor(best, m);
    best = (o < best) ? o : best;
  }
  if (l16 == 0) {
    const int id = (int)(best & 0xffffffffull);
    idxh[lvl * NROWS + row] = id;
    fidx[lvl * NROWS + row] = (float)id;
    idsh[rr] = id;
  }
  __syncthreads();

  // ---- phase C: verified k_update math inline ----
  const int id = idsh[rr];
  const float4* cpc = reinterpret_cast<const float4*>(
      cb_l + (size_t)id * DIM + l16 * 16);
  float4* tp = reinterpret_cast<float4*>(tq + obase);
  float nn[16];
  float e = 0.f;
  #pragma unroll
  for (int j = 0; j < 4; ++j) {
    float4 c = cpc[j];
    float n0 = rj[j].x - c.x, n1 = rj[j].y - c.y;
    float n2 = rj[j].z - c.z, n3 = rj[j].w - c.w;
    nn[4 * j + 0] = n0; nn[4 * j + 1] = n1; nn[4 * j + 2] = n2; nn[4 * j + 3] = n3;
    e += (n0 * n0 + n1 * n1) + (n2 * n2 + n3 * n3);
    float4 tv;
    if (lvl == 0) {
      tv = c;
    } else {
      tv = tp[j];
      tv.x += c.x; tv.y += c.y; tv.z += c.z; tv.w += c.w;
    }
    if (lvl == 3) {
      tv.x = xj[j].x + (tv.x - xj[j].x); tv.y = xj[j].y + (tv.y - xj[j].y);
      tv.z = xj[j].z + (tv.z - xj[j].z); tv.w = xj[j].w + (tv.w - xj[j].w);
    }
    tp[j] = tv;
  }

  if (lvl < 3) {
    unsigned w[8];
    #pragma unroll
    for (int k = 0; k < 8; ++k)
      w[k] = (unsigned)f2bf(nn[2 * k]) | ((unsigned)f2bf(nn[2 * k + 1]) << 16);
    // packed rhi write (block == row tile)
    unsigned short* base = rhi + (size_t)blockIdx.x * 4096;
    const int ks = l16 >> 1;
    const int kb0 = (l16 & 1) * 2;
    *reinterpret_cast<uint4*>(base + ks * 512 + kb0 * 128 + rr * 8) =
        make_uint4(w[0], w[1], w[2], w[3]);
    *reinterpret_cast<uint4*>(base + ks * 512 + (kb0 + 1) * 128 + rr * 8) =
        make_uint4(w[4], w[5], w[6], w[7]);
  }

  sred[tid] = e;
  __syncthreads();
  if (tid < 16) {
    float s = 0.f;
    #pragma unroll
    for (int k = 0; k < 16; ++k) s += sred[tid * 16 + k];
    rsum[tid] = s;
    if (lvl < 3) rowsq_o[blockIdx.x * 16 + tid] = s;
  }
  __syncthreads();
  if (tid == 0) {
    float p = 0.f;
    #pragma unroll
    for (int k = 0; k < 16; ++k) p += rsum[k];
    part[blockIdx.x] = p;
  }
}

// ============ loss finalize (unchanged) ============
__global__ __launch_bounds__(256) void k_loss(const float* __restrict__ part,
                                              float* __restrict__ out) {
  __shared__ float s[256];
  const int tid = threadIdx.x;
  float means[4];
  for (int l = 0; l < 4; ++l) {
    float sum = 0.f;
    for (int i = tid; i < 2048; i += 256) sum += part[l * 2048 + i];
    s[tid] = sum;
    __syncthreads();
    for (int st = 128; st > 0; st >>= 1) {
      if (tid < st) s[tid] += s[tid + st];
      __syncthreads();
    }
    means[l] = s[0] * (1.0f / 8388608.0f);
    __syncthreads();
  }
  if (tid == 0) {
    float t = ((means[0] + means[1]) + means[2]) + means[3];
    float loss = t * 0.25f;
    out[0] = loss;
    out[1] = loss;
  }
}

extern "C" void kernel_launch(void* const* d_in, const int* in_sizes, int n_in,
                              void* d_out, int out_size, void* d_ws, size_t ws_size,
                              hipStream_t stream) {
  const float* x  = (const float*)d_in[0];
  const float* cb = (const float*)d_in[1];
  float* out = (float*)d_out;
  float* ws  = (float*)d_ws;

  // ws layout (float units)
  unsigned short* rhi = (unsigned short*)ws;                         // 4194304 f
  unsigned short* chi = (unsigned short*)(ws + 4194304);             // 524288 f
  unsigned* survq  = (unsigned*)(ws + 4194304 + 524288);             // 2097152 f
  unsigned* counts = (unsigned*)(ws + 4194304 + 524288 + 2097152);   // 32768 f
  int* idxh        = (int*)(ws + 4194304 + 524288 + 2097152 + 32768);  // 131072 f
  float* bv    = ws + 4194304 + 524288 + 2097152 + 32768 + 131072;   // 4096
  float* rowsq = bv + 4096;                                          // 32768
  float* part  = rowsq + 32768;                                      // 8192

  float* tq      = out;                    // total_quant accumulates in d_out
  float* lossout = out + 8388608;
  float* fidx    = out + 8388610;

  k_bnorm<<<16, 256, 0, stream>>>(cb, bv);
  k_csplit<<<256, 256, 0, stream>>>(cb, chi);
  k_prep<<<2048, 256, 0, stream>>>(x, rhi, rowsq);

  for (int l = 0; l < NLEV; ++l) {
    k_screen<<<512, 512, 0, stream>>>(rhi, chi + (size_t)l * KCODES * DIM,
                                      bv + l * KCODES, rowsq, survq, counts);
    k_exupd<<<2048, 256, 0, stream>>>(x, cb, bv, rowsq, survq, counts,
                                      idxh, fidx, tq, part + l * 2048,
                                      rowsq, rhi, l);
  }

  k_loss<<<1, 256, 0, stream>>>(part, lossout);
}